// Round 9
// baseline (225.104 us; speedup 1.0000x reference)
//
#include <hip/hip_runtime.h>
#include <hip/hip_cooperative_groups.h>

namespace cg = cooperative_groups;

typedef _Float16 f16x8 __attribute__((ext_vector_type(8)));
typedef float    f32x4 __attribute__((ext_vector_type(4)));
typedef float    f32x16 __attribute__((ext_vector_type(16)));
typedef unsigned int u32;

#define N_CTX 16384
#define N_Q   4096
#define DIM   100
#define THR   4.0f

union FragU { unsigned int u[4]; f16x8 v; };

#define MFMA32(a, b, c) __builtin_amdgcn_mfma_f32_32x32x16_f16((a), (b), (c), 0, 0, 0)
#define GLOAD_LDS(g, l) __builtin_amdgcn_global_load_lds( \
    (const __attribute__((address_space(1))) u32*)(const void*)(g), \
    (__attribute__((address_space(3))) u32*)(void*)(l), 16, 0, 0)

// ---------------- fused prep ----------------
// qbS: per 32-j block an 8KB image; element (j,d) at byte
//      (d>>3)*512 + (j&31)*16 + (d&7)*2.  d=100 -> t_j, d>100 -> 0.
// cbH: [16384][128] fp16 rows: d<100 -> ctx*w3, d==100 -> 1.0, else 0.
// qTS: per 32-j block an 8KB image; element (d, jl) at byte
//      (d>>5)*2048 + (jl>>3)*512 + (d&31)*16 + (jl&7)*2. d=100 row = ones.
__global__ void prep_all(const float* __restrict__ q, const float* __restrict__ ctx,
                         const float* __restrict__ ker,
                         unsigned short* __restrict__ qbS, unsigned short* __restrict__ qTS,
                         unsigned short* __restrict__ cbH, float* __restrict__ a) {
    int b = blockIdx.x;
    int tid = threadIdx.x;
    if (b < 16) {
        int j = b * 256 + tid;
        const float* row = q + (size_t)j * DIM;
        float buf[100];
        float acc = 0.f;
        #pragma unroll
        for (int d4 = 0; d4 < 25; ++d4) {
            #pragma unroll
            for (int e = 0; e < 4; ++e) {
                float v = row[4 * d4 + e];
                buf[4 * d4 + e] = v;
                acc += v * ker[100 + 4 * d4 + e];
            }
        }
        char* img = (char*)qbS + (size_t)(j >> 5) * 8192 + (j & 31) * 16;
        #pragma unroll
        for (int o = 0; o < 16; ++o) {
            f16x8 h;
            #pragma unroll
            for (int e = 0; e < 8; ++e) {
                int d = 8 * o + e;
                float v = (d < DIM) ? buf[d] : (d == DIM ? acc : 0.f);
                h[e] = (_Float16)v;
            }
            *reinterpret_cast<f16x8*>(img + o * 512) = h;
        }
    } else if (b < 80) {
        int i = (b - 16) * 256 + tid;
        const float* row = ctx + (size_t)i * DIM;
        float acc = 0.f;
        #pragma unroll
        for (int d = 0; d < DIM; ++d) acc += row[d] * ker[d];
        a[i] = acc;
    } else if (b < 144) {
        int i = (b - 80) * 256 + tid;
        const float* row = ctx + (size_t)i * DIM;
        unsigned short* orow = cbH + (size_t)i * 128;
        #pragma unroll
        for (int c = 0; c < 16; ++c) {
            f16x8 h;
            #pragma unroll
            for (int e = 0; e < 8; ++e) {
                int d = 8 * c + e;
                float v = (d < DIM) ? row[d] * ker[200 + d] : (d == DIM ? 1.f : 0.f);
                h[e] = (_Float16)v;
            }
            *reinterpret_cast<f16x8*>(orow + 8 * c) = h;
        }
    } else {
        __shared__ _Float16 ldsT[100][64];
        int j0 = (b - 144) * 64;
        int r = tid >> 2, c = tid & 3;
        const float* row = q + (size_t)(j0 + r) * DIM + c * 25;
        #pragma unroll
        for (int k = 0; k < 25; ++k) ldsT[c * 25 + k][r] = (_Float16)row[k];
        __syncthreads();
        #pragma unroll
        for (int k = 0; k < 4; ++k) {
            int ci = tid + k * 256;
            int jb = ci >> 9;
            int rem = ci & 511;
            int dt = rem >> 7, rem2 = rem & 127;
            int o = rem2 >> 5, rr = rem2 & 31;
            int d = dt * 32 + rr;
            f16x8 v;
            #pragma unroll
            for (int e = 0; e < 8; ++e) {
                int jl = jb * 32 + 8 * o + e;
                v[e] = (d < DIM) ? ldsT[d][jl] : (d == DIM ? (_Float16)1.f : (_Float16)0.f);
            }
            char* dst = (char*)qTS + (size_t)((j0 >> 5) + jb) * 8192
                        + dt * 2048 + o * 512 + rr * 16;
            *reinterpret_cast<f16x8*>(dst) = v;
        }
    }
}

// ---------------- main fused attention ----------------
__global__ __launch_bounds__(256, 4) void attn_main(
    const unsigned short* __restrict__ qbS, const unsigned short* __restrict__ qTS,
    const unsigned short* __restrict__ cbH,
    _Float16* __restrict__ Ub, float* __restrict__ mb,
    float* __restrict__ lb, float* __restrict__ mtb)
{
    __shared__ __align__(16) char stageMem[2][16384];

    const int tid  = threadIdx.x;
    const int w    = tid >> 6;
    const int lane = tid & 63;
    const int hi   = lane >> 5;
    const int c31  = lane & 31;
    const int it   = blockIdx.x;
    const int js   = blockIdx.y;
    const int JS   = gridDim.y;
    const int R    = (N_Q / 32) / JS;
    const int iw0  = it * 128 + w * 32;

    f16x8 cbF[7];
    {
        const unsigned short* crow = cbH + (size_t)(iw0 + c31) * 128 + 8 * hi;
        #pragma unroll
        for (int kk = 0; kk < 7; ++kk)
            cbF[kk] = *reinterpret_cast<const f16x8*>(crow + kk * 16);
    }

    f32x16 U0 = {}, U1 = {}, U2 = {}, U3 = {};
    float m = -INFINITY, mtrue = -INFINITY;

    const int bb0 = js * R;
    const int seg = w * 2;
    const int l16 = lane * 16;

    auto stage_fn = [&](int buf, int bb) {
        const char* gq = (const char*)qbS + (size_t)bb * 8192;
        const char* gt = (const char*)qTS + (size_t)bb * 8192;
        char* lq = stageMem[buf];
        #pragma unroll
        for (int k = 0; k < 2; ++k)
            GLOAD_LDS(gq + (seg + k) * 1024 + l16, lq + (seg + k) * 1024);
        #pragma unroll
        for (int k = 0; k < 2; ++k)
            GLOAD_LDS(gt + (seg + k) * 1024 + l16, lq + 8192 + (seg + k) * 1024);
    };

    stage_fn(0, bb0);
    __syncthreads();
    int cur = 0;

    for (int r = 0; r < R; ++r) {
        if (r + 1 < R) stage_fn(cur ^ 1, bb0 + r + 1);

        const char* qbL = stageMem[cur];
        const char* qTL = stageMem[cur] + 8192;

        // ---- QK^T (t folded at k=100) ----
        f32x16 sacc = {};
        __builtin_amdgcn_s_setprio(1);
        #pragma unroll
        for (int kk = 0; kk < 7; ++kk) {
            f16x8 aq = *reinterpret_cast<const f16x8*>(qbL + kk * 1024 + l16);
            sacc = MFMA32(aq, cbF[kk], sacc);
        }
        __builtin_amdgcn_s_setprio(0);

        float sc[16];
        #pragma unroll
        for (int q16 = 0; q16 < 16; ++q16) sc[q16] = sacc[q16];

        float t0 = fmaxf(sc[0], sc[1]),  t1 = fmaxf(sc[2], sc[3]);
        float t2 = fmaxf(sc[4], sc[5]),  t3 = fmaxf(sc[6], sc[7]);
        float t4 = fmaxf(sc[8], sc[9]),  t5 = fmaxf(sc[10], sc[11]);
        float t6 = fmaxf(sc[12], sc[13]), t7 = fmaxf(sc[14], sc[15]);
        t0 = fmaxf(t0, t1); t2 = fmaxf(t2, t3);
        t4 = fmaxf(t4, t5); t6 = fmaxf(t6, t7);
        float tm = fmaxf(fmaxf(t0, t2), fmaxf(t4, t6));
        mtrue = fmaxf(mtrue, tm);

        if (__any(tm > m + THR)) {
            float tmf = fmaxf(tm, __shfl_xor(tm, 32, 64));
            float mn = fmaxf(m, tmf);
            float scale = __expf(m - mn);
            U0 *= scale; U1 *= scale; U2 *= scale; U3 *= scale;
            m = mn;
        }

        #pragma unroll
        for (int q16 = 0; q16 < 16; ++q16) sc[q16] = __expf(sc[q16] - m);

        // ---- P -> PV B-operand (pkrtz pack + half exchange) ----
        unsigned int pk[8], pr[8];
        #pragma unroll
        for (int h2 = 0; h2 < 8; ++h2) {
            auto p2 = __builtin_amdgcn_cvt_pkrtz(sc[2 * h2], sc[2 * h2 + 1]);
            pk[h2] = __builtin_bit_cast(unsigned int, p2);
            pr[h2] = (unsigned int)__shfl_xor((int)pk[h2], 32, 64);
        }
        FragU f0, f1;
        f0.u[0] = hi ? pr[2] : pk[0];
        f0.u[1] = hi ? pr[3] : pk[1];
        f0.u[2] = hi ? pk[2] : pr[0];
        f0.u[3] = hi ? pk[3] : pr[1];
        f1.u[0] = hi ? pr[6] : pk[4];
        f1.u[1] = hi ? pr[7] : pk[5];
        f1.u[2] = hi ? pk[6] : pr[4];
        f1.u[3] = hi ? pk[7] : pr[5];

        // ---- PV ----
        __builtin_amdgcn_s_setprio(1);
        {
            f16x8 a0 = *reinterpret_cast<const f16x8*>(qTL + l16);
            f16x8 a1 = *reinterpret_cast<const f16x8*>(qTL + 1024 + l16);
            U0 = MFMA32(a0, f0.v, U0);
            U0 = MFMA32(a1, f1.v, U0);
        }
        {
            f16x8 a0 = *reinterpret_cast<const f16x8*>(qTL + 2048 + l16);
            f16x8 a1 = *reinterpret_cast<const f16x8*>(qTL + 3072 + l16);
            U1 = MFMA32(a0, f0.v, U1);
            U1 = MFMA32(a1, f1.v, U1);
        }
        {
            f16x8 a0 = *reinterpret_cast<const f16x8*>(qTL + 4096 + l16);
            f16x8 a1 = *reinterpret_cast<const f16x8*>(qTL + 5120 + l16);
            U2 = MFMA32(a0, f0.v, U2);
            U2 = MFMA32(a1, f1.v, U2);
        }
        {
            f16x8 a0 = *reinterpret_cast<const f16x8*>(qTL + 6144 + l16);
            f16x8 a1 = *reinterpret_cast<const f16x8*>(qTL + 7168 + l16);
            U3 = MFMA32(a0, f0.v, U3);
            U3 = MFMA32(a1, f1.v, U3);
        }
        __builtin_amdgcn_s_setprio(0);

        __syncthreads();
        cur ^= 1;
    }

    mtrue = fmaxf(mtrue, __shfl_xor(mtrue, 32, 64));
    float ltmp = __shfl_xor(U3[0], 32, 64);
    float lfull = hi ? U3[0] : ltmp;

    int irow = iw0 + c31;
    if (hi == 0) {
        mb [(size_t)js * N_CTX + irow] = m;
        lb [(size_t)js * N_CTX + irow] = lfull;
        mtb[(size_t)js * N_CTX + irow] = mtrue;
    }
    _Float16* ub = Ub + (((size_t)js * 128 + it) * DIM) * 128 + w * 32 + c31;
    #pragma unroll
    for (int r = 0; r < 16; ++r) {
        int dl = (r & 3) + 8 * (r >> 2) + 4 * hi;
        ub[(size_t)dl * 128]        = (_Float16)U0[r];
        ub[(size_t)(32 + dl) * 128] = (_Float16)U1[r];
        ub[(size_t)(64 + dl) * 128] = (_Float16)U2[r];
        if (96 + dl < DIM) ub[(size_t)(96 + dl) * 128] = (_Float16)U3[r];
    }
}

// ---------------- fused cooperative epilogue ----------------
// 512 blocks x 256 thr, block b owns rows [b*32, +32).
// P1: merge JS splits -> G cols 0..299, mf in LDS, block max -> gmaxp.
// sync. P2: global M; exp weights; partial hp (fp16) + zp. sync.
// P3: Z, h; write G cols 300..399 from staged ctx.
template<int JS>
__global__ __launch_bounds__(256, 2) void epilogue(
    const _Float16* __restrict__ Ub, const float* __restrict__ mb,
    const float* __restrict__ lb, const float* __restrict__ mtb,
    const float* __restrict__ a, const float* __restrict__ ctx,
    float* __restrict__ G,
    float* __restrict__ gmaxp, float* __restrict__ zp,
    _Float16* __restrict__ hpg)
{
    __shared__ float ctxL[32][104];
    __shared__ float mfL[32];
    __shared__ float red[64];
    __shared__ float hL[104];

    cg::grid_group grid = cg::this_grid();

    const int b   = blockIdx.x;
    const int tid = threadIdx.x;
    const int i32 = tid & 31, seg = tid >> 5;
    const int row = b * 32 + i32;
    const int iblk = row >> 7, il = row & 127;

    // stage ctx rows
    for (int idx = tid; idx < 32 * DIM; idx += 256) {
        int r = idx / DIM, d = idx - r * DIM;
        ctxL[r][d] = ctx[(size_t)(b * 32 + r) * DIM + d];
    }
    __syncthreads();

    // ---- P1: combine splits ----
    float mw[JS];
    float M = -INFINITY;
    #pragma unroll
    for (int js = 0; js < JS; ++js) {
        mw[js] = mb[(size_t)js * N_CTX + row];
        M = fmaxf(M, mw[js]);
    }
    float ew[JS];
    float L = 0.f, Mt = -INFINITY;
    #pragma unroll
    for (int js = 0; js < JS; ++js) {
        ew[js] = __expf(mw[js] - M);
        L += lb[(size_t)js * N_CTX + row] * ew[js];
        Mt = fmaxf(Mt, mtb[(size_t)js * N_CTX + row]);
    }
    if (seg == 0) mfL[i32] = a[row] + Mt;
    float invL = 1.f / L;
    for (int d = seg; d < DIM; d += 8) {
        float u = 0.f;
        #pragma unroll
        for (int js = 0; js < JS; ++js)
            u += (float)Ub[(((size_t)js * 128 + iblk) * DIM + d) * 128 + il] * ew[js];
        float ua = u * invL;
        float cv = ctxL[i32][d];
        size_t base = (size_t)row * 400;
        G[base + d]       = cv;
        G[base + 100 + d] = ua;
        G[base + 200 + d] = ua * cv;
    }
    __syncthreads();
    if (tid < 32) {
        float v = mfL[tid];
        #pragma unroll
        for (int o = 16; o > 0; o >>= 1) v = fmaxf(v, __shfl_xor(v, o, 64));
        if (tid == 0) gmaxp[b] = v;
    }
    grid.sync();

    // ---- P2: global max, exp weights, hp partial ----
    {
        float v = fmaxf(gmaxp[2 * tid], gmaxp[2 * tid + 1]);   // 512 values
        #pragma unroll
        for (int o = 32; o > 0; o >>= 1) v = fmaxf(v, __shfl_xor(v, o, 64));
        if ((tid & 63) == 0) red[tid >> 6] = v;
        __syncthreads();
        float gm = fmaxf(fmaxf(red[0], red[1]), fmaxf(red[2], red[3]));
        if (tid < 32) mfL[tid] = __expf(mfL[tid] - gm);
        __syncthreads();
        if (tid == 0) {
            float z = 0.f;
            #pragma unroll
            for (int r = 0; r < 32; ++r) z += mfL[r];
            zp[b] = z;
        }
        if (tid < DIM) {
            float s = 0.f;
            #pragma unroll
            for (int r = 0; r < 32; ++r) s += mfL[r] * ctxL[r][tid];
            hpg[b * DIM + tid] = (_Float16)s;
        }
    }
    grid.sync();

    // ---- P3: Z, h, G cols 300..399 ----
    {
        float z = zp[2 * tid] + zp[2 * tid + 1];
        #pragma unroll
        for (int o = 32; o > 0; o >>= 1) z += __shfl_xor(z, o, 64);
        if ((tid & 63) == 0) red[tid >> 6] = z;
        __syncthreads();
        float Z = red[0] + red[1] + red[2] + red[3];
        if (tid < DIM) {
            float s = 0.f;
            for (int bb = 0; bb < 512; ++bb) s += (float)hpg[bb * DIM + tid];
            hL[tid] = s / Z;
        }
        __syncthreads();
        for (int idx = tid; idx < 32 * DIM; idx += 256) {
            int r = idx / DIM, d = idx - r * DIM;
            G[(size_t)(b * 32 + r) * 400 + 300 + d] = ctxL[r][d] * hL[d];
        }
    }
}

// ---------------- fallback (non-cooperative) epilogue path ----------------
template<int JS>
__global__ void combine(const _Float16* __restrict__ Ub, const float* __restrict__ mb,
                        const float* __restrict__ lb, const float* __restrict__ mtb,
                        const float* __restrict__ a, const float* __restrict__ ctx,
                        float* __restrict__ G, float* __restrict__ mfull)
{
    int tid = threadIdx.x;
    int i32 = tid & 31, seg = tid >> 5;
    int row = blockIdx.x * 32 + i32;
    int iblk = row >> 7, il = row & 127;

    float mw[JS];
    float M = -INFINITY;
    #pragma unroll
    for (int js = 0; js < JS; ++js) {
        mw[js] = mb[(size_t)js * N_CTX + row];
        M = fmaxf(M, mw[js]);
    }
    float ew[JS];
    float L = 0.f, Mt = -INFINITY;
    #pragma unroll
    for (int js = 0; js < JS; ++js) {
        ew[js] = __expf(mw[js] - M);
        L += lb[(size_t)js * N_CTX + row] * ew[js];
        Mt = fmaxf(Mt, mtb[(size_t)js * N_CTX + row]);
    }
    if (seg == 0) mfull[row] = a[row] + Mt;
    float invL = 1.f / L;
    for (int d = seg; d < DIM; d += 8) {
        float u = 0.f;
        #pragma unroll
        for (int js = 0; js < JS; ++js)
            u += (float)Ub[(((size_t)js * 128 + iblk) * DIM + d) * 128 + il] * ew[js];
        float ua = u * invL;
        float cv = ctx[(size_t)row * DIM + d];
        size_t base = (size_t)row * 400;
        G[base + d]       = cv;
        G[base + 100 + d] = ua;
        G[base + 200 + d] = ua * cv;
    }
}

__global__ void kernel_h(const float* __restrict__ mfull, const float* __restrict__ ctx,
                         float* __restrict__ hp) {
    __shared__ float sm[256];
    __shared__ float smh[8][104];
    int t = threadIdx.x;
    float v = -INFINITY;
    for (int i = t; i < N_CTX; i += 256) v = fmaxf(v, mfull[i]);
    sm[t] = v; __syncthreads();
    for (int s = 128; s > 0; s >>= 1) { if (t < s) sm[t] = fmaxf(sm[t], sm[t + s]); __syncthreads(); }
    float M = sm[0];
    __syncthreads();
    float z = 0.f;
    for (int i = t; i < N_CTX; i += 256) z += __expf(mfull[i] - M);
    sm[t] = z; __syncthreads();
    for (int s = 128; s > 0; s >>= 1) { if (t < s) sm[t] += sm[t + s]; __syncthreads(); }
    float Z = sm[0];
    __syncthreads();

    int rr = t >> 5, d32 = t & 31;
    int i0 = blockIdx.x * 64;
    float a0 = 0.f, a1 = 0.f, a2 = 0.f, a3 = 0.f;
    for (int g = 0; g < 8; ++g) {
        int row = i0 + g * 8 + rr;
        float bw = __expf(mfull[row] - M);
        const float* cr = ctx + (size_t)row * DIM;
        a0 += bw * cr[d32];
        a1 += bw * cr[d32 + 32];
        a2 += bw * cr[d32 + 64];
        if (d32 < 4) a3 += bw * cr[d32 + 96];
    }
    smh[rr][d32]      = a0;
    smh[rr][d32 + 32] = a1;
    smh[rr][d32 + 64] = a2;
    if (d32 < 4) smh[rr][d32 + 96] = a3;
    __syncthreads();
    if (t < DIM) {
        float s = 0.f;
        #pragma unroll
        for (int g = 0; g < 8; ++g) s += smh[g][t];
        hp[blockIdx.x * 128 + t] = s / Z;
    }
}

__global__ void kernel_hred(const float* __restrict__ hp, float* __restrict__ h) {
    __shared__ float sm[4][128];
    int t = threadIdx.x;
    int d = t & 127, rep = t >> 7;
    float s = 0.f;
    if (d < DIM) for (int b = 0; b < 64; ++b) s += hp[(rep * 64 + b) * 128 + d];
    sm[rep][d] = s;
    __syncthreads();
    if (rep == 0 && d < DIM) h[d] = sm[0][d] + sm[1][d] + sm[2][d] + sm[3][d];
}

__global__ void kernel_g4(const float* __restrict__ ctx, const float* __restrict__ h,
                          float* __restrict__ G) {
    int idx = blockIdx.x * 256 + threadIdx.x;
    if (idx >= N_CTX * DIM) return;
    int i = idx / DIM;
    int d = idx - i * DIM;
    G[(size_t)i * 400 + 300 + d] = ctx[idx] * h[d];
}

// ---------------- launcher ----------------
extern "C" void kernel_launch(void* const* d_in, const int* in_sizes, int n_in,
                              void* d_out, int out_size, void* d_ws, size_t ws_size,
                              hipStream_t stream) {
    const float* ctx = (const float*)d_in[0];
    const float* q   = (const float*)d_in[1];
    const float* ker = (const float*)d_in[2];
    float* G = (float*)d_out;

    char* ws = (char*)d_ws;
    unsigned short* qbS   = (unsigned short*)(ws);                 // 1,048,576
    unsigned short* qTS   = (unsigned short*)(ws + 1048576);       // 1,048,576
    unsigned short* cbH   = (unsigned short*)(ws + 2097152);       // 4,194,304
    float*          a     = (float*)(ws + 6291456);                // 65,536
    float*          mfull = (float*)(ws + 6356992);                // 65,536 (fallback) / gmaxp+zp (coop)
    float*          hp    = (float*)(ws + 6422528);                // 131,072 (fallback) / hpg (coop)
    float*          h     = (float*)(ws + 6553600);                // 512
    const size_t fixed = 6554112;

    float*    gmaxp = (float*)(ws + 6356992);
    float*    zp    = (float*)(ws + 6356992 + 2048);
    _Float16* hpg   = (_Float16*)(ws + 6422528);

    int JS = 8;
    if (fixed + 8ull * 3473408ull > ws_size) JS = 4;
    if (fixed + 4ull * 3473408ull > ws_size) JS = 2;

    _Float16* Ub  = (_Float16*)(ws + fixed);
    size_t ubB    = (size_t)JS * 3276800ull;
    float*    mb  = (float*)(ws + fixed + ubB);
    float*    lb  = (float*)(ws + fixed + ubB + (size_t)JS * 65536ull);
    float*    mtb = (float*)(ws + fixed + ubB + (size_t)JS * 131072ull);

    int coop = 0, dev = 0;
    (void)hipGetDevice(&dev);
    (void)hipDeviceGetAttribute(&coop, hipDeviceAttributeCooperativeLaunch, dev);

    prep_all<<<dim3(208), dim3(256), 0, stream>>>(q, ctx, ker, qbS, qTS, cbH, a);
    attn_main<<<dim3(128, JS), dim3(256), 0, stream>>>(qbS, qTS, cbH, Ub, mb, lb, mtb);

    if (coop && JS == 8) {
        void* args[] = { (void*)&Ub, (void*)&mb, (void*)&lb, (void*)&mtb,
                         (void*)&a, (void*)&ctx, (void*)&G,
                         (void*)&gmaxp, (void*)&zp, (void*)&hpg };
        hipError_t err = hipLaunchCooperativeKernel((void*)epilogue<8>,
                                                    dim3(512), dim3(256), args, 0, stream);
        if (err == hipSuccess) return;
    }

    // fallback path
    if (JS == 8)
        combine<8><<<dim3(512), dim3(256), 0, stream>>>(Ub, mb, lb, mtb, a, ctx, G, mfull);
    else if (JS == 4)
        combine<4><<<dim3(512), dim3(256), 0, stream>>>(Ub, mb, lb, mtb, a, ctx, G, mfull);
    else
        combine<2><<<dim3(512), dim3(256), 0, stream>>>(Ub, mb, lb, mtb, a, ctx, G, mfull);
    kernel_h<<<dim3(256), dim3(256), 0, stream>>>(mfull, ctx, hp);
    kernel_hred<<<dim3(1), dim3(512), 0, stream>>>(hp, h);
    kernel_g4<<<dim3(6400), dim3(256), 0, stream>>>(ctx, h, G);
}

// Round 10
// 110.991 us; speedup vs baseline: 2.0281x; 2.0281x over previous
//
#include <hip/hip_runtime.h>

typedef _Float16 f16x8 __attribute__((ext_vector_type(8)));
typedef float    f32x4 __attribute__((ext_vector_type(4)));
typedef float    f32x16 __attribute__((ext_vector_type(16)));
typedef unsigned int u32;

#define N_CTX 16384
#define N_Q   4096
#define DIM   100
#define THR   4.0f

union FragU { unsigned int u[4]; f16x8 v; };

#define MFMA32(a, b, c) __builtin_amdgcn_mfma_f32_32x32x16_f16((a), (b), (c), 0, 0, 0)
#define GLOAD_LDS(g, l) __builtin_amdgcn_global_load_lds( \
    (const __attribute__((address_space(1))) u32*)(const void*)(g), \
    (__attribute__((address_space(3))) u32*)(void*)(l), 16, 0, 0)

// ---------------- fused prep ----------------
// qbS: per 32-j block an 8KB image; element (j,d) at byte
//      (d>>3)*512 + (j&31)*16 + (d&7)*2.  d=100 -> t_j, d>100 -> 0.
// cbH: [16384][128] fp16 rows: d<100 -> ctx*w3, d==100 -> 1.0, else 0.
// qTS: per 32-j block an 8KB image; element (d, jl) at byte
//      (d>>5)*2048 + (jl>>3)*512 + (d&31)*16 + (jl&7)*2. d=100 row = ones.
__global__ void prep_all(const float* __restrict__ q, const float* __restrict__ ctx,
                         const float* __restrict__ ker,
                         unsigned short* __restrict__ qbS, unsigned short* __restrict__ qTS,
                         unsigned short* __restrict__ cbH, float* __restrict__ a) {
    int b = blockIdx.x;
    int tid = threadIdx.x;
    if (b < 16) {
        int j = b * 256 + tid;
        const float* row = q + (size_t)j * DIM;
        float buf[100];
        float acc = 0.f;
        #pragma unroll
        for (int d4 = 0; d4 < 25; ++d4) {
            #pragma unroll
            for (int e = 0; e < 4; ++e) {
                float v = row[4 * d4 + e];
                buf[4 * d4 + e] = v;
                acc += v * ker[100 + 4 * d4 + e];
            }
        }
        char* img = (char*)qbS + (size_t)(j >> 5) * 8192 + (j & 31) * 16;
        #pragma unroll
        for (int o = 0; o < 16; ++o) {
            f16x8 h;
            #pragma unroll
            for (int e = 0; e < 8; ++e) {
                int d = 8 * o + e;
                float v = (d < DIM) ? buf[d] : (d == DIM ? acc : 0.f);
                h[e] = (_Float16)v;
            }
            *reinterpret_cast<f16x8*>(img + o * 512) = h;
        }
    } else if (b < 80) {
        int i = (b - 16) * 256 + tid;
        const float* row = ctx + (size_t)i * DIM;
        float acc = 0.f;
        #pragma unroll
        for (int d = 0; d < DIM; ++d) acc += row[d] * ker[d];
        a[i] = acc;
    } else if (b < 144) {
        int i = (b - 80) * 256 + tid;
        const float* row = ctx + (size_t)i * DIM;
        unsigned short* orow = cbH + (size_t)i * 128;
        #pragma unroll
        for (int c = 0; c < 16; ++c) {
            f16x8 h;
            #pragma unroll
            for (int e = 0; e < 8; ++e) {
                int d = 8 * c + e;
                float v = (d < DIM) ? row[d] * ker[200 + d] : (d == DIM ? 1.f : 0.f);
                h[e] = (_Float16)v;
            }
            *reinterpret_cast<f16x8*>(orow + 8 * c) = h;
        }
    } else {
        __shared__ _Float16 ldsT[100][64];
        int j0 = (b - 144) * 64;
        int r = tid >> 2, c = tid & 3;
        const float* row = q + (size_t)(j0 + r) * DIM + c * 25;
        #pragma unroll
        for (int k = 0; k < 25; ++k) ldsT[c * 25 + k][r] = (_Float16)row[k];
        __syncthreads();
        #pragma unroll
        for (int k = 0; k < 4; ++k) {
            int ci = tid + k * 256;
            int jb = ci >> 9;
            int rem = ci & 511;
            int dt = rem >> 7, rem2 = rem & 127;
            int o = rem2 >> 5, rr = rem2 & 31;
            int d = dt * 32 + rr;
            f16x8 v;
            #pragma unroll
            for (int e = 0; e < 8; ++e) {
                int jl = jb * 32 + 8 * o + e;
                v[e] = (d < DIM) ? ldsT[d][jl] : (d == DIM ? (_Float16)1.f : (_Float16)0.f);
            }
            char* dst = (char*)qTS + (size_t)((j0 >> 5) + jb) * 8192
                        + dt * 2048 + o * 512 + rr * 16;
            *reinterpret_cast<f16x8*>(dst) = v;
        }
    }
}

// ---------------- main fused attention (unchanged from round 9) ----------------
__global__ __launch_bounds__(256, 4) void attn_main(
    const unsigned short* __restrict__ qbS, const unsigned short* __restrict__ qTS,
    const unsigned short* __restrict__ cbH,
    _Float16* __restrict__ Ub, float* __restrict__ mb,
    float* __restrict__ lb, float* __restrict__ mtb)
{
    __shared__ __align__(16) char stageMem[2][16384];

    const int tid  = threadIdx.x;
    const int w    = tid >> 6;
    const int lane = tid & 63;
    const int hi   = lane >> 5;
    const int c31  = lane & 31;
    const int it   = blockIdx.x;
    const int js   = blockIdx.y;
    const int JS   = gridDim.y;
    const int R    = (N_Q / 32) / JS;
    const int iw0  = it * 128 + w * 32;

    f16x8 cbF[7];
    {
        const unsigned short* crow = cbH + (size_t)(iw0 + c31) * 128 + 8 * hi;
        #pragma unroll
        for (int kk = 0; kk < 7; ++kk)
            cbF[kk] = *reinterpret_cast<const f16x8*>(crow + kk * 16);
    }

    f32x16 U0 = {}, U1 = {}, U2 = {}, U3 = {};
    float m = -INFINITY, mtrue = -INFINITY;

    const int bb0 = js * R;
    const int seg = w * 2;
    const int l16 = lane * 16;

    auto stage_fn = [&](int buf, int bb) {
        const char* gq = (const char*)qbS + (size_t)bb * 8192;
        const char* gt = (const char*)qTS + (size_t)bb * 8192;
        char* lq = stageMem[buf];
        #pragma unroll
        for (int k = 0; k < 2; ++k)
            GLOAD_LDS(gq + (seg + k) * 1024 + l16, lq + (seg + k) * 1024);
        #pragma unroll
        for (int k = 0; k < 2; ++k)
            GLOAD_LDS(gt + (seg + k) * 1024 + l16, lq + 8192 + (seg + k) * 1024);
    };

    stage_fn(0, bb0);
    __syncthreads();
    int cur = 0;

    for (int r = 0; r < R; ++r) {
        if (r + 1 < R) stage_fn(cur ^ 1, bb0 + r + 1);

        const char* qbL = stageMem[cur];
        const char* qTL = stageMem[cur] + 8192;

        // ---- QK^T (t folded at k=100) ----
        f32x16 sacc = {};
        __builtin_amdgcn_s_setprio(1);
        #pragma unroll
        for (int kk = 0; kk < 7; ++kk) {
            f16x8 aq = *reinterpret_cast<const f16x8*>(qbL + kk * 1024 + l16);
            sacc = MFMA32(aq, cbF[kk], sacc);
        }
        __builtin_amdgcn_s_setprio(0);

        float sc[16];
        #pragma unroll
        for (int q16 = 0; q16 < 16; ++q16) sc[q16] = sacc[q16];

        float t0 = fmaxf(sc[0], sc[1]),  t1 = fmaxf(sc[2], sc[3]);
        float t2 = fmaxf(sc[4], sc[5]),  t3 = fmaxf(sc[6], sc[7]);
        float t4 = fmaxf(sc[8], sc[9]),  t5 = fmaxf(sc[10], sc[11]);
        float t6 = fmaxf(sc[12], sc[13]), t7 = fmaxf(sc[14], sc[15]);
        t0 = fmaxf(t0, t1); t2 = fmaxf(t2, t3);
        t4 = fmaxf(t4, t5); t6 = fmaxf(t6, t7);
        float tm = fmaxf(fmaxf(t0, t2), fmaxf(t4, t6));
        mtrue = fmaxf(mtrue, tm);

        if (__any(tm > m + THR)) {
            float tmf = fmaxf(tm, __shfl_xor(tm, 32, 64));
            float mn = fmaxf(m, tmf);
            float scale = __expf(m - mn);
            U0 *= scale; U1 *= scale; U2 *= scale; U3 *= scale;
            m = mn;
        }

        #pragma unroll
        for (int q16 = 0; q16 < 16; ++q16) sc[q16] = __expf(sc[q16] - m);

        // ---- P -> PV B-operand (pkrtz pack + half exchange) ----
        unsigned int pk[8], pr[8];
        #pragma unroll
        for (int h2 = 0; h2 < 8; ++h2) {
            auto p2 = __builtin_amdgcn_cvt_pkrtz(sc[2 * h2], sc[2 * h2 + 1]);
            pk[h2] = __builtin_bit_cast(unsigned int, p2);
            pr[h2] = (unsigned int)__shfl_xor((int)pk[h2], 32, 64);
        }
        FragU f0, f1;
        f0.u[0] = hi ? pr[2] : pk[0];
        f0.u[1] = hi ? pr[3] : pk[1];
        f0.u[2] = hi ? pk[2] : pr[0];
        f0.u[3] = hi ? pk[3] : pr[1];
        f1.u[0] = hi ? pr[6] : pk[4];
        f1.u[1] = hi ? pr[7] : pk[5];
        f1.u[2] = hi ? pk[6] : pr[4];
        f1.u[3] = hi ? pk[7] : pr[5];

        // ---- PV ----
        __builtin_amdgcn_s_setprio(1);
        {
            f16x8 a0 = *reinterpret_cast<const f16x8*>(qTL + l16);
            f16x8 a1 = *reinterpret_cast<const f16x8*>(qTL + 1024 + l16);
            U0 = MFMA32(a0, f0.v, U0);
            U0 = MFMA32(a1, f1.v, U0);
        }
        {
            f16x8 a0 = *reinterpret_cast<const f16x8*>(qTL + 2048 + l16);
            f16x8 a1 = *reinterpret_cast<const f16x8*>(qTL + 3072 + l16);
            U1 = MFMA32(a0, f0.v, U1);
            U1 = MFMA32(a1, f1.v, U1);
        }
        {
            f16x8 a0 = *reinterpret_cast<const f16x8*>(qTL + 4096 + l16);
            f16x8 a1 = *reinterpret_cast<const f16x8*>(qTL + 5120 + l16);
            U2 = MFMA32(a0, f0.v, U2);
            U2 = MFMA32(a1, f1.v, U2);
        }
        {
            f16x8 a0 = *reinterpret_cast<const f16x8*>(qTL + 6144 + l16);
            f16x8 a1 = *reinterpret_cast<const f16x8*>(qTL + 7168 + l16);
            U3 = MFMA32(a0, f0.v, U3);
            U3 = MFMA32(a1, f1.v, U3);
        }
        __builtin_amdgcn_s_setprio(0);

        __syncthreads();
        cur ^= 1;
    }

    mtrue = fmaxf(mtrue, __shfl_xor(mtrue, 32, 64));
    float ltmp = __shfl_xor(U3[0], 32, 64);
    float lfull = hi ? U3[0] : ltmp;

    int irow = iw0 + c31;
    if (hi == 0) {
        mb [(size_t)js * N_CTX + irow] = m;
        lb [(size_t)js * N_CTX + irow] = lfull;
        mtb[(size_t)js * N_CTX + irow] = mtrue;
    }
    _Float16* ub = Ub + (((size_t)js * 128 + it) * DIM) * 128 + w * 32 + c31;
    #pragma unroll
    for (int r = 0; r < 16; ++r) {
        int dl = (r & 3) + 8 * (r >> 2) + 4 * hi;
        ub[(size_t)dl * 128]        = (_Float16)U0[r];
        ub[(size_t)(32 + dl) * 128] = (_Float16)U1[r];
        ub[(size_t)(64 + dl) * 128] = (_Float16)U2[r];
        if (96 + dl < DIM) ub[(size_t)(96 + dl) * 128] = (_Float16)U3[r];
    }
}

// ---------------- tail kernels ----------------

// mfull[i] = a[i] + max_js mtb[js][i]
template<int JS>
__global__ void kernel_mf(const float* __restrict__ a, const float* __restrict__ mtb,
                          float* __restrict__ mfull) {
    int i = blockIdx.x * 256 + threadIdx.x;
    float mt = -INFINITY;
    #pragma unroll
    for (int js = 0; js < JS; ++js) mt = fmaxf(mt, mtb[(size_t)js * N_CTX + i]);
    mfull[i] = a[i] + mt;
}

// redundant M/Z scan (L2-resident) + coalesced partial h for 64 rows
__global__ void kernel_h(const float* __restrict__ mfull, const float* __restrict__ ctx,
                         float* __restrict__ hp) {
    __shared__ float sm[256];
    __shared__ float smh[8][104];
    int t = threadIdx.x;
    float v = -INFINITY;
    for (int i = t; i < N_CTX; i += 256) v = fmaxf(v, mfull[i]);
    sm[t] = v; __syncthreads();
    for (int s = 128; s > 0; s >>= 1) { if (t < s) sm[t] = fmaxf(sm[t], sm[t + s]); __syncthreads(); }
    float M = sm[0];
    __syncthreads();
    float z = 0.f;
    for (int i = t; i < N_CTX; i += 256) z += __expf(mfull[i] - M);
    sm[t] = z; __syncthreads();
    for (int s = 128; s > 0; s >>= 1) { if (t < s) sm[t] += sm[t + s]; __syncthreads(); }
    float Z = sm[0];
    __syncthreads();

    int rr = t >> 5, d32 = t & 31;
    int i0 = blockIdx.x * 64;
    float a0 = 0.f, a1 = 0.f, a2 = 0.f, a3 = 0.f;
    for (int g = 0; g < 8; ++g) {
        int row = i0 + g * 8 + rr;
        float bw = __expf(mfull[row] - M);
        const float* cr = ctx + (size_t)row * DIM;
        a0 += bw * cr[d32];
        a1 += bw * cr[d32 + 32];
        a2 += bw * cr[d32 + 64];
        if (d32 < 4) a3 += bw * cr[d32 + 96];
    }
    smh[rr][d32]      = a0;
    smh[rr][d32 + 32] = a1;
    smh[rr][d32 + 64] = a2;
    if (d32 < 4) smh[rr][d32 + 96] = a3;
    __syncthreads();
    if (t < DIM) {
        float s = 0.f;
        #pragma unroll
        for (int g = 0; g < 8; ++g) s += smh[g][t];
        hp[blockIdx.x * 128 + t] = s / Z;
    }
}

__global__ void kernel_hred(const float* __restrict__ hp, float* __restrict__ h) {
    __shared__ float sm[4][128];
    int t = threadIdx.x;
    int d = t & 127, rep = t >> 7;
    float s = 0.f;
    if (d < DIM) for (int b = 0; b < 64; ++b) s += hp[(rep * 64 + b) * 128 + d];
    sm[rep][d] = s;
    __syncthreads();
    if (rep == 0 && d < DIM) h[d] = sm[0][d] + sm[1][d] + sm[2][d] + sm[3][d];
}

// ---------------- combine: merge splits + write ALL 400 G cols, coalesced ----
template<int JS>
__global__ __launch_bounds__(256, 4) void combine(
    const _Float16* __restrict__ Ub, const float* __restrict__ mb,
    const float* __restrict__ lb, const float* __restrict__ h,
    const float* __restrict__ ctx, float* __restrict__ G)
{
    __shared__ float ctxL[32][100];
    __shared__ float uaL[32][100];
    __shared__ float hL[100];

    const int b   = blockIdx.x;
    const int tid = threadIdx.x;

    for (int idx = tid; idx < 32 * DIM; idx += 256) {
        int r = idx / DIM, d = idx - r * DIM;
        ctxL[r][d] = ctx[(size_t)(b * 32 + r) * DIM + d];
    }
    if (tid < DIM) hL[tid] = h[tid];
    __syncthreads();

    {
        int i32 = tid & 31, seg = tid >> 5;
        int row = b * 32 + i32;
        int iblk = row >> 7, il = row & 127;
        float mw[JS];
        float M = -INFINITY;
        #pragma unroll
        for (int js = 0; js < JS; ++js) {
            mw[js] = mb[(size_t)js * N_CTX + row];
            M = fmaxf(M, mw[js]);
        }
        float ew[JS];
        float L = 0.f;
        #pragma unroll
        for (int js = 0; js < JS; ++js) {
            ew[js] = __expf(mw[js] - M);
            L += lb[(size_t)js * N_CTX + row] * ew[js];
        }
        float invL = 1.f / L;
        for (int d = seg; d < DIM; d += 8) {
            float u = 0.f;
            #pragma unroll
            for (int js = 0; js < JS; ++js)
                u += (float)Ub[(((size_t)js * 128 + iblk) * DIM + d) * 128 + il] * ew[js];
            uaL[i32][d] = u * invL;
        }
    }
    __syncthreads();

    // linear coalesced sweep over 32 rows x 400 cols
    float* gOut = G + (size_t)b * 32 * 400;
    for (int idx = tid; idx < 32 * 400; idx += 256) {
        int r = idx / 400, c = idx - r * 400;
        int sel = c / 100, d = c - sel * 100;
        float cv = ctxL[r][d];
        float val;
        if (sel == 0)      val = cv;
        else if (sel == 1) val = uaL[r][d];
        else if (sel == 2) val = uaL[r][d] * cv;
        else               val = cv * hL[d];
        gOut[idx] = val;
    }
}

// ---------------- launcher ----------------
extern "C" void kernel_launch(void* const* d_in, const int* in_sizes, int n_in,
                              void* d_out, int out_size, void* d_ws, size_t ws_size,
                              hipStream_t stream) {
    const float* ctx = (const float*)d_in[0];
    const float* q   = (const float*)d_in[1];
    const float* ker = (const float*)d_in[2];
    float* G = (float*)d_out;

    char* ws = (char*)d_ws;
    unsigned short* qbS   = (unsigned short*)(ws);                 // 1,048,576
    unsigned short* qTS   = (unsigned short*)(ws + 1048576);       // 1,048,576
    unsigned short* cbH   = (unsigned short*)(ws + 2097152);       // 4,194,304
    float*          a     = (float*)(ws + 6291456);                // 65,536
    float*          mfull = (float*)(ws + 6356992);                // 65,536
    float*          hp    = (float*)(ws + 6422528);                // 131,072
    float*          h     = (float*)(ws + 6553600);                // 512
    const size_t fixed = 6554112;

    int JS = 8;
    if (fixed + 8ull * 3473408ull > ws_size) JS = 4;
    if (fixed + 4ull * 3473408ull > ws_size) JS = 2;

    _Float16* Ub  = (_Float16*)(ws + fixed);
    size_t ubB    = (size_t)JS * 3276800ull;
    float*    mb  = (float*)(ws + fixed + ubB);
    float*    lb  = (float*)(ws + fixed + ubB + (size_t)JS * 65536ull);
    float*    mtb = (float*)(ws + fixed + ubB + (size_t)JS * 131072ull);

    prep_all<<<dim3(208), dim3(256), 0, stream>>>(q, ctx, ker, qbS, qTS, cbH, a);
    attn_main<<<dim3(128, JS), dim3(256), 0, stream>>>(qbS, qTS, cbH, Ub, mb, lb, mtb);

    if (JS == 8) {
        kernel_mf<8><<<dim3(64), dim3(256), 0, stream>>>(a, mtb, mfull);
        kernel_h<<<dim3(256), dim3(256), 0, stream>>>(mfull, ctx, hp);
        kernel_hred<<<dim3(1), dim3(512), 0, stream>>>(hp, h);
        combine<8><<<dim3(512), dim3(256), 0, stream>>>(Ub, mb, lb, h, ctx, G);
    } else if (JS == 4) {
        kernel_mf<4><<<dim3(64), dim3(256), 0, stream>>>(a, mtb, mfull);
        kernel_h<<<dim3(256), dim3(256), 0, stream>>>(mfull, ctx, hp);
        kernel_hred<<<dim3(1), dim3(512), 0, stream>>>(hp, h);
        combine<4><<<dim3(512), dim3(256), 0, stream>>>(Ub, mb, lb, h, ctx, G);
    } else {
        kernel_mf<2><<<dim3(64), dim3(256), 0, stream>>>(a, mtb, mfull);
        kernel_h<<<dim3(256), dim3(256), 0, stream>>>(mfull, ctx, hp);
        kernel_hred<<<dim3(1), dim3(512), 0, stream>>>(hp, h);
        combine<2><<<dim3(512), dim3(256), 0, stream>>>(Ub, mb, lb, h, ctx, G);
    }
}